// Round 7
// baseline (3118.933 us; speedup 1.0000x reference)
//
#include <hip/hip_runtime.h>
#include <hip/hip_bf16.h>
#include <stdint.h>

#define S 2048
#define D 64
#define H 4096
#define NB 8

typedef __bf16 bf16;
typedef __attribute__((ext_vector_type(8))) __bf16 bf16x8;
typedef __attribute__((ext_vector_type(4))) __bf16 bf16x4;
typedef __attribute__((ext_vector_type(4))) float f32x4;

// Raw LDS-DMA, invisible to the compiler's waitcnt pass (no auto vmcnt(0)).
// M0 = wave-uniform LDS byte offset; HW adds lane*16B. (R5-verified.)
__device__ __forceinline__ void dma16_raw(const bf16* g, uint32_t m0_bytes) {
  uint32_t m0s = __builtin_amdgcn_readfirstlane(m0_bytes);
  asm volatile("s_mov_b32 m0, %1\n\t"
               "global_load_lds_dwordx4 %0, off"
               :: "v"(g), "s"(m0s) : "memory");
}

__device__ __forceinline__ uint32_t lds_off_bytes(const void* p) {
  return (uint32_t)(uintptr_t)(__attribute__((address_space(3))) const void*)p;
}

// ---------------------------------------------------------------------------
// Transpose + cast: W [K][N] f32  ->  Wt [N][K] bf16   (weights, once per call)
// ---------------------------------------------------------------------------
__global__ __launch_bounds__(256) void transpose_cast(const float* __restrict__ W,
                                                      bf16* __restrict__ Wt,
                                                      int K, int N) {
  __shared__ float tile[64][65];
  int k0 = blockIdx.y * 64, n0 = blockIdx.x * 64;
  int c = threadIdx.x & 63;
  int r4 = threadIdx.x >> 6;
#pragma unroll
  for (int i = 0; i < 16; ++i) {
    int r = i * 4 + r4;
    tile[r][c] = W[(size_t)(k0 + r) * N + n0 + c];
  }
  __syncthreads();
#pragma unroll
  for (int i = 0; i < 16; ++i) {
    int r = i * 4 + r4;
    Wt[(size_t)(n0 + r) * K + k0 + c] = (bf16)tile[c][r];
  }
}

// ---------------------------------------------------------------------------
// Elementwise cast f32 -> bf16 (for Q, K). One float4 per thread.
// ---------------------------------------------------------------------------
__global__ __launch_bounds__(256) void cast_bf16(const float* __restrict__ x,
                                                 bf16* __restrict__ y) {
  int i = blockIdx.x * 256 + threadIdx.x;
  f32x4 v = ((const f32x4*)x)[i];
  bf16x4 o;
  o[0] = (bf16)v.x; o[1] = (bf16)v.y; o[2] = (bf16)v.z; o[3] = (bf16)v.w;
  ((bf16x4*)y)[i] = o;
}

// ---------------------------------------------------------------------------
// GEMM: C[M][N] = epilogue(scale * (A[M][K] @ Bt[N][K]^T) + bias[N])
// bf16 in, fp32 accum. 256x128 block tile, BK=32, 512 threads (8 waves as
// 4Mx2N of 64x64 wave tiles) -> 24 waves/CU at 3 blocks/CU (48 KB LDS).
// K-loop: 2 buffers, R5-style 2-barrier pipeline with raw-asm DMA:
//   barrier1: s_waitcnt vmcnt(3) (tile it landed; tile it+1 in flight)
//   8x ds_read_b128 fragments
//   barrier2: s_waitcnt lgkmcnt(0) (all waves' reads done)
//   stage tile it+2 into buf it%2; 16 MFMA.
// LDS XOR-swizzle (verified 0 bank conflicts) retained.
// ---------------------------------------------------------------------------
template <int RELU, int OUTBF16>
__global__ __launch_bounds__(512, 6) void gemm_bt(const bf16* __restrict__ A,
                                                  const bf16* __restrict__ Bt,
                                                  const float* __restrict__ bias,
                                                  void* __restrict__ Cv,
                                                  float scale,
                                                  int M, int N, int K,
                                                  long strideA, long strideB,
                                                  long strideC) {
  // smem (bf16 elems): A bufs [0,8192),[8192,16384); B bufs [16384,20480),[20480,24576)
  __shared__ __align__(16) bf16 smem[24576];  // 48 KB
  int tid = threadIdx.x;
  int lane = tid & 63;
  int w = tid >> 6;

  int m0 = blockIdx.y * 256, n0 = blockIdx.x * 128;
  const bf16* Ab = A + (size_t)blockIdx.z * strideA;
  const bf16* Btb = Bt + (size_t)blockIdx.z * strideB;

  // staging: thread t covers A rows t>>2 (0..127) and 128+(t>>2); B row t>>2.
  // Granule lands at LDS chunk l&3 -> fetch global chunk (l&3)^((l>>3)&3).
  int grow = tid >> 2;
  int gcol = (((lane & 3) ^ ((lane >> 3) & 3)) * 8);
  const bf16* gA0 = Ab + (size_t)(m0 + grow) * K + gcol;
  const bf16* gA1 = gA0 + (size_t)128 * K;
  const bf16* gB0 = Btb + (size_t)(n0 + grow) * K + gcol;

  // wave-uniform LDS byte offsets: A buf b at b*16384 B (+8192 B second half);
  // B buf b at 32768 + b*8192 B; wave section w*1024 B.
  uint32_t ldsBase = lds_off_bytes(&smem[0]);
  uint32_t wb = (uint32_t)(w * 1024);
  uint32_t mA[2], mB[2];
  mA[0] = ldsBase + wb;          mA[1] = ldsBase + 16384 + wb;
  mB[0] = ldsBase + 32768 + wb;  mB[1] = ldsBase + 40960 + wb;

  int mw = (w & 3) * 64, nw = (w >> 2) * 64;
  int lr = lane & 15;
  int ck = lane >> 4;
  int swz = (ck ^ ((lr >> 1) & 3)) * 8;
  const bf16* paBase = smem + (size_t)(mw + lr) * 32 + swz;          // + buf*8192
  const bf16* pbBase = smem + 16384 + (size_t)(nw + lr) * 32 + swz;  // + buf*4096

  f32x4 zero = {0.f, 0.f, 0.f, 0.f};
  f32x4 acc[4][4];
#pragma unroll
  for (int mt = 0; mt < 4; ++mt)
#pragma unroll
    for (int nt = 0; nt < 4; ++nt) acc[mt][nt] = zero;

  const int niter = K / 32;

#define STAGE(buf, koff)                                 \
  do {                                                   \
    dma16_raw(gA0 + (koff), mA[buf]);                    \
    dma16_raw(gA1 + (koff), mA[buf] + 8192);             \
    dma16_raw(gB0 + (koff), mB[buf]);                    \
  } while (0)

  // prologue: tiles 0 and 1 in flight (6 outstanding per thread)
  STAGE(0, 0);
  STAGE(1, 32);

  for (int it = 0; it < niter; ++it) {
    int buf = it & 1;
    // tile `it` landed (own 3 oldest drained; rendezvous covers other waves)
    asm volatile("s_waitcnt vmcnt(3)\n\ts_barrier" ::: "memory");
    const bf16* pa = paBase + buf * 8192;
    const bf16* pb = pbBase + buf * 4096;
    bf16x8 af[4], bfr[4];
#pragma unroll
    for (int mt = 0; mt < 4; ++mt) af[mt] = *(const bf16x8*)(pa + mt * (16 * 32));
#pragma unroll
    for (int nt = 0; nt < 4; ++nt) bfr[nt] = *(const bf16x8*)(pb + nt * (16 * 32));
    // all waves finished reading `buf` -> safe to overwrite with tile it+2
    asm volatile("s_waitcnt lgkmcnt(0)\n\ts_barrier" ::: "memory");
    // tail: re-stage last tile to keep the 3-issues-per-iter vmcnt invariant
    int kpre = it + 2 < niter ? (it + 2) * 32 : (niter - 1) * 32;
    STAGE(buf, kpre);
#pragma unroll
    for (int mt = 0; mt < 4; ++mt)
#pragma unroll
      for (int nt = 0; nt < 4; ++nt)
        acc[mt][nt] = __builtin_amdgcn_mfma_f32_16x16x32_bf16(af[mt], bfr[nt],
                                                              acc[mt][nt], 0, 0, 0);
  }
#undef STAGE
  // drain leftover DMAs before LDS is reused by the next block
  asm volatile("s_waitcnt vmcnt(0)" ::: "memory");

  // epilogue; C/D layout: col = lane&15, row = (lane>>4)*4 + reg
  int mbase = m0 + mw + (lane >> 4) * 4;
  int nbase = n0 + nw + (lane & 15);
#pragma unroll
  for (int mt = 0; mt < 4; ++mt) {
#pragma unroll
    for (int nt = 0; nt < 4; ++nt) {
      int n = nbase + nt * 16;
      float bv = bias ? bias[n] : 0.f;
#pragma unroll
      for (int reg = 0; reg < 4; ++reg) {
        int m = mbase + mt * 16 + reg;
        float v = acc[mt][nt][reg] * scale + bv;
        if (RELU) v = fmaxf(v, 0.f);
        if (OUTBF16) {
          bf16* C = (bf16*)Cv + (size_t)blockIdx.z * strideC;
          C[(size_t)m * N + n] = (bf16)v;
        } else {
          float* C = (float*)Cv + (size_t)blockIdx.z * strideC;
          C[(size_t)m * N + n] = v;
        }
      }
    }
  }
}

// ---------------------------------------------------------------------------
// Fused softmax (over k) + attn @ V.  4 q-rows per block, 256 threads.
// ---------------------------------------------------------------------------
__global__ __launch_bounds__(256) void softmax_av(const float* __restrict__ adj,
                                                  const float* __restrict__ V,
                                                  float* __restrict__ out,
                                                  long adjStride) {
  int z = blockIdx.y;
  const float* adjb = adj + (size_t)z * adjStride;
  const float* Vb = V + (size_t)z * (S * D);
  float* outb = out + (size_t)z * (S * D);
  int q0 = blockIdx.x * 4;
  __shared__ __align__(16) float attnL[4][S];
  __shared__ float red[4][4][64];
  __shared__ float rsum[4];
  int tid = threadIdx.x;
  int w = tid >> 6, lane = tid & 63;

  const float* rowp = adjb + (size_t)(q0 + w) * S;
  float lm = -1e30f;
  f32x4 rv[8];
#pragma unroll
  for (int k = 0; k < 8; ++k) {
    rv[k] = *(const f32x4*)&rowp[lane * 4 + k * 256];
    lm = fmaxf(fmaxf(fmaxf(rv[k].x, rv[k].y), fmaxf(rv[k].z, rv[k].w)), lm);
  }
#pragma unroll
  for (int off = 32; off > 0; off >>= 1) lm = fmaxf(lm, __shfl_xor(lm, off));
  float s = 0.f;
#pragma unroll
  for (int k = 0; k < 8; ++k) {
    f32x4 e;
    e.x = __expf(rv[k].x - lm);
    e.y = __expf(rv[k].y - lm);
    e.z = __expf(rv[k].z - lm);
    e.w = __expf(rv[k].w - lm);
    *(f32x4*)&attnL[w][lane * 4 + k * 256] = e;
    s += e.x + e.y + e.z + e.w;
  }
#pragma unroll
  for (int off = 32; off > 0; off >>= 1) s += __shfl_xor(s, off);
  if (lane == 0) rsum[w] = s;
  __syncthreads();

  float acc0 = 0.f, acc1 = 0.f, acc2 = 0.f, acc3 = 0.f;
  int kbase = w * 512;
  for (int kk = 0; kk < 512; kk += 4) {
    int k = kbase + kk;
    float v0 = Vb[(size_t)(k + 0) * D + lane];
    float v1 = Vb[(size_t)(k + 1) * D + lane];
    float v2 = Vb[(size_t)(k + 2) * D + lane];
    float v3 = Vb[(size_t)(k + 3) * D + lane];
    f32x4 a0 = *(const f32x4*)&attnL[0][k];
    f32x4 a1 = *(const f32x4*)&attnL[1][k];
    f32x4 a2 = *(const f32x4*)&attnL[2][k];
    f32x4 a3 = *(const f32x4*)&attnL[3][k];
    acc0 += a0.x * v0 + a0.y * v1 + a0.z * v2 + a0.w * v3;
    acc1 += a1.x * v0 + a1.y * v1 + a1.z * v2 + a1.w * v3;
    acc2 += a2.x * v0 + a2.y * v1 + a2.z * v2 + a2.w * v3;
    acc3 += a3.x * v0 + a3.y * v1 + a3.z * v2 + a3.w * v3;
  }
  red[w][0][lane] = acc0;
  red[w][1][lane] = acc1;
  red[w][2][lane] = acc2;
  red[w][3][lane] = acc3;
  __syncthreads();
  int r = tid >> 6, d = tid & 63;
  float v = red[0][r][d] + red[1][r][d] + red[2][r][d] + red[3][r][d];
  outb[(size_t)(q0 + r) * D + d] = v / rsum[r];
}

// ---------------------------------------------------------------------------
extern "C" void kernel_launch(void* const* d_in, const int* in_sizes, int n_in,
                              void* d_out, int out_size, void* d_ws, size_t ws_size,
                              hipStream_t stream) {
  const float* Q  = (const float*)d_in[0];
  const float* Km = (const float*)d_in[1];
  const float* V  = (const float*)d_in[2];
  const float* W1 = (const float*)d_in[3];
  const float* b1 = (const float*)d_in[4];
  const float* W2 = (const float*)d_in[5];
  const float* b2 = (const float*)d_in[6];
  float* out = (float*)d_out;
  char* ws = (char*)d_ws;

  // layout: W1t 16M | W2t 16M | Qb16 2M | Kb16 2M | X (Sc bf16 / adj f32,
  // aliased) G*16M | h G*16M.  footprint = 36M + G*32M bytes.
  bf16* W1t  = (bf16*)ws;
  bf16* W2t  = (bf16*)(ws + 16777216);
  bf16* Qb16 = (bf16*)(ws + 33554432);
  bf16* Kb16 = (bf16*)(ws + 35651584);

  transpose_cast<<<dim3(H / 64, S / 64), 256, 0, stream>>>(W1, W1t, S, H);
  transpose_cast<<<dim3(S / 64, H / 64), 256, 0, stream>>>(W2, W2t, H, S);
  cast_bf16<<<dim3(NB * S * D / 1024), 256, 0, stream>>>(Q, Qb16);
  cast_bf16<<<dim3(NB * S * D / 1024), 256, 0, stream>>>(Km, Kb16);

  int G = 1;
  if (ws_size >= 306184192ULL) G = 8;        // 292 MiB
  else if (ws_size >= 171966464ULL) G = 4;   // 164 MiB (R6 proved ws>=192MiB)
  else if (ws_size >= 104857600ULL) G = 2;   // 100 MiB

  bf16* Sc   = (bf16*)(ws + 37748736);
  float* adj = (float*)(ws + 37748736);
  bf16* h    = (bf16*)(ws + 37748736 + (size_t)G * 16777216);

  for (int b0 = 0; b0 < NB; b0 += G) {
    // scores = (Q @ K^T) / 8 via MFMA (A = Qb16, Bt = Kb16, K-dim = 64)
    gemm_bt<0, 1><<<dim3(S / 128, S / 256, G), 512, 0, stream>>>(
        Qb16 + (size_t)b0 * S * D, Kb16 + (size_t)b0 * S * D, nullptr, Sc,
        0.125f, S, S, D, (long)S * D, (long)S * D, (long)S * S);
    gemm_bt<1, 1><<<dim3(H / 128, S / 256, G), 512, 0, stream>>>(
        Sc, W1t, b1, h, 1.0f, S, H, S, (long)S * S, 0L, (long)S * H);
    gemm_bt<0, 0><<<dim3(S / 128, S / 256, G), 512, 0, stream>>>(
        h, W2t, b2, adj, 1.0f, S, S, H, (long)S * H, 0L, (long)S * S);
    softmax_av<<<dim3(S / 4, G), 256, 0, stream>>>(
        adj, V + (size_t)b0 * S * D, out + (size_t)b0 * S * D, (long)S * S);
  }
}

// Round 8
// 918.636 us; speedup vs baseline: 3.3952x; 3.3952x over previous
//
#include <hip/hip_runtime.h>
#include <hip/hip_bf16.h>
#include <stdint.h>

#define S 2048
#define D 64
#define H 4096
#define NB 8

typedef __bf16 bf16;
typedef __attribute__((ext_vector_type(8))) __bf16 bf16x8;
typedef __attribute__((ext_vector_type(4))) __bf16 bf16x4;
typedef __attribute__((ext_vector_type(4))) float f32x4;

// Raw LDS-DMA, invisible to the compiler's waitcnt pass (no auto vmcnt(0)).
// M0 = wave-uniform LDS byte offset; HW adds lane*16B. (R5-verified.)
__device__ __forceinline__ void dma16_raw(const bf16* g, uint32_t m0_bytes) {
  uint32_t m0s = __builtin_amdgcn_readfirstlane(m0_bytes);
  asm volatile("s_mov_b32 m0, %1\n\t"
               "global_load_lds_dwordx4 %0, off"
               :: "v"(g), "s"(m0s) : "memory");
}

__device__ __forceinline__ uint32_t lds_off_bytes(const void* p) {
  return (uint32_t)(uintptr_t)(__attribute__((address_space(3))) const void*)p;
}

// ---------------------------------------------------------------------------
// Transpose + cast: W [K][N] f32  ->  Wt [N][K] bf16   (weights, once per call)
// ---------------------------------------------------------------------------
__global__ __launch_bounds__(256) void transpose_cast(const float* __restrict__ W,
                                                      bf16* __restrict__ Wt,
                                                      int K, int N) {
  __shared__ float tile[64][65];
  int k0 = blockIdx.y * 64, n0 = blockIdx.x * 64;
  int c = threadIdx.x & 63;
  int r4 = threadIdx.x >> 6;
#pragma unroll
  for (int i = 0; i < 16; ++i) {
    int r = i * 4 + r4;
    tile[r][c] = W[(size_t)(k0 + r) * N + n0 + c];
  }
  __syncthreads();
#pragma unroll
  for (int i = 0; i < 16; ++i) {
    int r = i * 4 + r4;
    Wt[(size_t)(n0 + r) * K + k0 + c] = (bf16)tile[c][r];
  }
}

// ---------------------------------------------------------------------------
// Elementwise cast f32 -> bf16 (for Q, K). One float4 per thread.
// ---------------------------------------------------------------------------
__global__ __launch_bounds__(256) void cast_bf16(const float* __restrict__ x,
                                                 bf16* __restrict__ y) {
  int i = blockIdx.x * 256 + threadIdx.x;
  f32x4 v = ((const f32x4*)x)[i];
  bf16x4 o;
  o[0] = (bf16)v.x; o[1] = (bf16)v.y; o[2] = (bf16)v.z; o[3] = (bf16)v.w;
  ((bf16x4*)y)[i] = o;
}

// ---------------------------------------------------------------------------
// GEMM: C[M][N] = epilogue(scale * (A[M][K] @ Bt[N][K]^T) + bias[N])
// bf16 in, fp32 accum. 128x256 block tile, BK=32, 256 threads (4 waves as
// 2Mx2N of 64x128 wave tiles — raises FLOP per LDS byte 1.35x over 64x64;
// the R6 counters showed the K-loop is LDS-BW-bound).
// Regs: acc 4x8 f32x4 = 128 AGPR + ~80 VGPR < 256 cap from (256,2) — no
// spill (R7 post-mortem: launch_bounds 2nd arg caps regs; spill = 2GB HBM).
// K-loop: 2 buffers, R5-verified 2-barrier raw-asm-DMA pipeline:
//   barrier1: s_waitcnt vmcnt(6)  (tile it landed; tile it+1 in flight)
//   12x ds_read_b128 fragments
//   barrier2: s_waitcnt lgkmcnt(0); stage tile it+2 (6 DMA); 32 MFMA.
// LDS XOR-swizzle (verified 0 bank conflicts) retained.
// ---------------------------------------------------------------------------
template <int RELU, int OUTBF16>
__global__ __launch_bounds__(256, 2) void gemm_bt(const bf16* __restrict__ A,
                                                  const bf16* __restrict__ Bt,
                                                  const float* __restrict__ bias,
                                                  void* __restrict__ Cv,
                                                  float scale,
                                                  int M, int N, int K,
                                                  long strideA, long strideB,
                                                  long strideC) {
  // smem (bf16 elems): A bufs [0,4096),[4096,8192);
  //                    B bufs [8192,16384),[16384,24576).  48 KB total.
  __shared__ __align__(16) bf16 smem[24576];
  int tid = threadIdx.x;
  int lane = tid & 63;
  int w = tid >> 6;

  int m0 = blockIdx.y * 128, n0 = blockIdx.x * 256;
  const bf16* Ab = A + (size_t)blockIdx.z * strideA;
  const bf16* Btb = Bt + (size_t)blockIdx.z * strideB;

  // staging: thread t covers row t>>2 (0..63) of each 64-row group.
  // Granule lands at LDS chunk l&3 -> fetch global chunk (l&3)^((l>>3)&3).
  int grow = tid >> 2;
  int gcol = (((lane & 3) ^ ((lane >> 3) & 3)) * 8);
  const bf16* gA0 = Ab + (size_t)(m0 + grow) * K + gcol;
  const bf16* gA1 = gA0 + (size_t)64 * K;
  const bf16* gB0 = Btb + (size_t)(n0 + grow) * K + gcol;
  const bf16* gB1 = gB0 + (size_t)64 * K;
  const bf16* gB2 = gB0 + (size_t)128 * K;
  const bf16* gB3 = gB0 + (size_t)192 * K;

  // wave-uniform LDS byte offsets: A buf b at b*8192 B; B buf b at
  // 16384 + b*16384 B; wave section w*1024 B; +4096 B per 64-row group.
  uint32_t ldsBase = lds_off_bytes(&smem[0]);
  uint32_t wb = (uint32_t)(w * 1024);
  uint32_t mA[2], mB[2];
  mA[0] = ldsBase + wb;          mA[1] = ldsBase + 8192 + wb;
  mB[0] = ldsBase + 16384 + wb;  mB[1] = ldsBase + 32768 + wb;

  int mw = (w & 1) * 64, nw = (w >> 1) * 128;
  int lr = lane & 15;
  int ck = lane >> 4;
  int swz = (ck ^ ((lr >> 1) & 3)) * 8;
  const bf16* paBase = smem + (size_t)(mw + lr) * 32 + swz;         // + buf*4096
  const bf16* pbBase = smem + 8192 + (size_t)(nw + lr) * 32 + swz;  // + buf*8192

  f32x4 zero = {0.f, 0.f, 0.f, 0.f};
  f32x4 acc[4][8];
#pragma unroll
  for (int mt = 0; mt < 4; ++mt)
#pragma unroll
    for (int nt = 0; nt < 8; ++nt) acc[mt][nt] = zero;

  const int niter = K / 32;

#define STAGE(buf, koff)                                 \
  do {                                                   \
    dma16_raw(gA0 + (koff), mA[buf]);                    \
    dma16_raw(gA1 + (koff), mA[buf] + 4096);             \
    dma16_raw(gB0 + (koff), mB[buf]);                    \
    dma16_raw(gB1 + (koff), mB[buf] + 4096);             \
    dma16_raw(gB2 + (koff), mB[buf] + 8192);             \
    dma16_raw(gB3 + (koff), mB[buf] + 12288);            \
  } while (0)

  // prologue: tiles 0 and 1 in flight (12 outstanding per thread)
  STAGE(0, 0);
  STAGE(1, 32);

  for (int it = 0; it < niter; ++it) {
    int buf = it & 1;
    // tile `it` landed (own 6 oldest drained; rendezvous covers other waves)
    asm volatile("s_waitcnt vmcnt(6)\n\ts_barrier" ::: "memory");
    const bf16* pa = paBase + buf * 4096;
    const bf16* pb = pbBase + buf * 8192;
    bf16x8 af[4], bfr[8];
#pragma unroll
    for (int mt = 0; mt < 4; ++mt) af[mt] = *(const bf16x8*)(pa + mt * (16 * 32));
#pragma unroll
    for (int nt = 0; nt < 8; ++nt) bfr[nt] = *(const bf16x8*)(pb + nt * (16 * 32));
    // all waves finished reading `buf` -> safe to overwrite with tile it+2
    asm volatile("s_waitcnt lgkmcnt(0)\n\ts_barrier" ::: "memory");
    // tail: re-stage last tile to keep the 6-issues-per-iter vmcnt invariant
    int kpre = it + 2 < niter ? (it + 2) * 32 : (niter - 1) * 32;
    STAGE(buf, kpre);
#pragma unroll
    for (int mt = 0; mt < 4; ++mt)
#pragma unroll
      for (int nt = 0; nt < 8; ++nt)
        acc[mt][nt] = __builtin_amdgcn_mfma_f32_16x16x32_bf16(af[mt], bfr[nt],
                                                              acc[mt][nt], 0, 0, 0);
  }
#undef STAGE
  // drain leftover DMAs before LDS is reused by the next block
  asm volatile("s_waitcnt vmcnt(0)" ::: "memory");

  // epilogue; C/D layout: col = lane&15, row = (lane>>4)*4 + reg
  int mbase = m0 + mw + (lane >> 4) * 4;
  int nbase = n0 + nw + (lane & 15);
#pragma unroll
  for (int mt = 0; mt < 4; ++mt) {
#pragma unroll
    for (int nt = 0; nt < 8; ++nt) {
      int n = nbase + nt * 16;
      float bv = bias ? bias[n] : 0.f;
#pragma unroll
      for (int reg = 0; reg < 4; ++reg) {
        int m = mbase + mt * 16 + reg;
        float v = acc[mt][nt][reg] * scale + bv;
        if (RELU) v = fmaxf(v, 0.f);
        if (OUTBF16) {
          bf16* C = (bf16*)Cv + (size_t)blockIdx.z * strideC;
          C[(size_t)m * N + n] = (bf16)v;
        } else {
          float* C = (float*)Cv + (size_t)blockIdx.z * strideC;
          C[(size_t)m * N + n] = v;
        }
      }
    }
  }
}

// ---------------------------------------------------------------------------
// Fused softmax (over k) + attn @ V.  4 q-rows per block, 256 threads.
// ---------------------------------------------------------------------------
__global__ __launch_bounds__(256) void softmax_av(const float* __restrict__ adj,
                                                  const float* __restrict__ V,
                                                  float* __restrict__ out,
                                                  long adjStride) {
  int z = blockIdx.y;
  const float* adjb = adj + (size_t)z * adjStride;
  const float* Vb = V + (size_t)z * (S * D);
  float* outb = out + (size_t)z * (S * D);
  int q0 = blockIdx.x * 4;
  __shared__ __align__(16) float attnL[4][S];
  __shared__ float red[4][4][64];
  __shared__ float rsum[4];
  int tid = threadIdx.x;
  int w = tid >> 6, lane = tid & 63;

  const float* rowp = adjb + (size_t)(q0 + w) * S;
  float lm = -1e30f;
  f32x4 rv[8];
#pragma unroll
  for (int k = 0; k < 8; ++k) {
    rv[k] = *(const f32x4*)&rowp[lane * 4 + k * 256];
    lm = fmaxf(fmaxf(fmaxf(rv[k].x, rv[k].y), fmaxf(rv[k].z, rv[k].w)), lm);
  }
#pragma unroll
  for (int off = 32; off > 0; off >>= 1) lm = fmaxf(lm, __shfl_xor(lm, off));
  float s = 0.f;
#pragma unroll
  for (int k = 0; k < 8; ++k) {
    f32x4 e;
    e.x = __expf(rv[k].x - lm);
    e.y = __expf(rv[k].y - lm);
    e.z = __expf(rv[k].z - lm);
    e.w = __expf(rv[k].w - lm);
    *(f32x4*)&attnL[w][lane * 4 + k * 256] = e;
    s += e.x + e.y + e.z + e.w;
  }
#pragma unroll
  for (int off = 32; off > 0; off >>= 1) s += __shfl_xor(s, off);
  if (lane == 0) rsum[w] = s;
  __syncthreads();

  float acc0 = 0.f, acc1 = 0.f, acc2 = 0.f, acc3 = 0.f;
  int kbase = w * 512;
  for (int kk = 0; kk < 512; kk += 4) {
    int k = kbase + kk;
    float v0 = Vb[(size_t)(k + 0) * D + lane];
    float v1 = Vb[(size_t)(k + 1) * D + lane];
    float v2 = Vb[(size_t)(k + 2) * D + lane];
    float v3 = Vb[(size_t)(k + 3) * D + lane];
    f32x4 a0 = *(const f32x4*)&attnL[0][k];
    f32x4 a1 = *(const f32x4*)&attnL[1][k];
    f32x4 a2 = *(const f32x4*)&attnL[2][k];
    f32x4 a3 = *(const f32x4*)&attnL[3][k];
    acc0 += a0.x * v0 + a0.y * v1 + a0.z * v2 + a0.w * v3;
    acc1 += a1.x * v0 + a1.y * v1 + a1.z * v2 + a1.w * v3;
    acc2 += a2.x * v0 + a2.y * v1 + a2.z * v2 + a2.w * v3;
    acc3 += a3.x * v0 + a3.y * v1 + a3.z * v2 + a3.w * v3;
  }
  red[w][0][lane] = acc0;
  red[w][1][lane] = acc1;
  red[w][2][lane] = acc2;
  red[w][3][lane] = acc3;
  __syncthreads();
  int r = tid >> 6, d = tid & 63;
  float v = red[0][r][d] + red[1][r][d] + red[2][r][d] + red[3][r][d];
  outb[(size_t)(q0 + r) * D + d] = v / rsum[r];
}

// ---------------------------------------------------------------------------
extern "C" void kernel_launch(void* const* d_in, const int* in_sizes, int n_in,
                              void* d_out, int out_size, void* d_ws, size_t ws_size,
                              hipStream_t stream) {
  const float* Q  = (const float*)d_in[0];
  const float* Km = (const float*)d_in[1];
  const float* V  = (const float*)d_in[2];
  const float* W1 = (const float*)d_in[3];
  const float* b1 = (const float*)d_in[4];
  const float* W2 = (const float*)d_in[5];
  const float* b2 = (const float*)d_in[6];
  float* out = (float*)d_out;
  char* ws = (char*)d_ws;

  // layout: W1t 16M | W2t 16M | Qb16 2M | Kb16 2M | X (Sc bf16 / adj f32,
  // aliased) G*16M | h G*16M.  footprint = 36M + G*32M bytes.
  bf16* W1t  = (bf16*)ws;
  bf16* W2t  = (bf16*)(ws + 16777216);
  bf16* Qb16 = (bf16*)(ws + 33554432);
  bf16* Kb16 = (bf16*)(ws + 35651584);

  transpose_cast<<<dim3(H / 64, S / 64), 256, 0, stream>>>(W1, W1t, S, H);
  transpose_cast<<<dim3(S / 64, H / 64), 256, 0, stream>>>(W2, W2t, H, S);
  cast_bf16<<<dim3(NB * S * D / 1024), 256, 0, stream>>>(Q, Qb16);
  cast_bf16<<<dim3(NB * S * D / 1024), 256, 0, stream>>>(Km, Kb16);

  int G = 1;
  if (ws_size >= 306184192ULL) G = 8;        // 292 MiB (R7 ran G=8 OK)
  else if (ws_size >= 171966464ULL) G = 4;
  else if (ws_size >= 104857600ULL) G = 2;

  bf16* Sc   = (bf16*)(ws + 37748736);
  float* adj = (float*)(ws + 37748736);
  bf16* h    = (bf16*)(ws + 37748736 + (size_t)G * 16777216);

  for (int b0 = 0; b0 < NB; b0 += G) {
    // scores = (Q @ K^T) / 8 via MFMA (A = Qb16, Bt = Kb16, K-dim = 64)
    gemm_bt<0, 1><<<dim3(S / 256, S / 128, G), 256, 0, stream>>>(
        Qb16 + (size_t)b0 * S * D, Kb16 + (size_t)b0 * S * D, nullptr, Sc,
        0.125f, S, S, D, (long)S * D, (long)S * D, (long)S * S);
    gemm_bt<1, 1><<<dim3(H / 256, S / 128, G), 256, 0, stream>>>(
        Sc, W1t, b1, h, 1.0f, S, H, S, (long)S * S, 0L, (long)S * H);
    gemm_bt<0, 0><<<dim3(S / 256, S / 128, G), 256, 0, stream>>>(
        h, W2t, b2, adj, 1.0f, S, S, H, (long)S * H, 0L, (long)S * S);
    softmax_av<<<dim3(S / 4, G), 256, 0, stream>>>(
        adj, V + (size_t)b0 * S * D, out + (size_t)b0 * S * D, (long)S * S);
  }
}